// Round 17
// baseline (51.841 us; speedup 1.0000x reference)
//
#include <hip/hip_runtime.h>

#define P   7
#define GS  7
#define D   21
#define HH  80
#define WW  80
#define CC  (D * GS * GS)        // 1029
#define PLANE (HH * WW)          // 6400 floats
#define IW  84                   // row stride: 16B-aligned rows
#define NSEG 5
#define SEGLEN 16

// fl32(1/7) = 0x3E124925 — the golden divides via reciprocal multiply.
__device__ __forceinline__ float recip7() {
    union { unsigned u; float f; } c; c.u = 0x3E124925u; return c.f;
}

// a*b + c with a HARD barrier between mul and add: no fma contraction ever.
__device__ __forceinline__ float mul_add_nofma(float a, float b, float c) {
    float t = a * b;
    asm volatile("" : "+v"(t));
    return t + c;
}

// ---------- prep: edges + parallel 2-level ballot compaction, one block -----
__global__ __launch_bounds__(1024) void prep_kernel(
    const float* __restrict__ rois, int R, int N,
    unsigned short* __restrict__ hshe,
    unsigned short* __restrict__ wswe,
    int* __restrict__ jlist, int* __restrict__ base)
{
    __shared__ unsigned char bsh[2048];
    __shared__ int wcnt[16][8];
    __shared__ int wbase[16][8];
    __shared__ int baseS[9];
    int tid = threadIdx.x, wave = tid >> 6, lane = tid & 63;

    for (int r = tid; r < R; r += 1024) {
        const float* roi = rois + (size_t)r * 5;
        bsh[r] = (unsigned char)(int)roi[0];

        float x1 = rintf(roi[1]) * 0.0625f;
        float y1 = rintf(roi[2]) * 0.0625f;
        float x2 = (rintf(roi[3]) + 1.0f) * 0.0625f;
        float y2 = (rintf(roi[4]) + 1.0f) * 0.0625f;
        float bin_w = fmaxf(x2 - x1, 0.1f) * recip7();
        float bin_h = fmaxf(y2 - y1, 0.1f) * recip7();
        asm volatile("" : "+v"(bin_w), "+v"(bin_h));

        #pragma unroll
        for (int g = 0; g < 7; ++g) {
            float hs_f = floorf(mul_add_nofma((float)g,       bin_h, y1));
            float he_f = ceilf (mul_add_nofma((float)(g + 1), bin_h, y1));
            float ws_f = floorf(mul_add_nofma((float)g,       bin_w, x1));
            float we_f = ceilf (mul_add_nofma((float)(g + 1), bin_w, x1));
            int hs = (int)fminf(fmaxf(hs_f, 0.0f), 80.0f);
            int he = (int)fminf(fmaxf(he_f, 0.0f), 80.0f);
            int ws = (int)fminf(fmaxf(ws_f, 0.0f), 80.0f);
            int we = (int)fminf(fmaxf(we_f, 0.0f), 80.0f);
            hshe[r * 7 + g] = (unsigned short)(hs | (he << 8));
            wswe[r * 7 + g] = (unsigned short)(ws | (we << 8));
        }
    }
    __syncthreads();

    int chunk = (R + 15) / 16;
    int rbeg = wave * chunk;
    int rend = min(rbeg + chunk, R);
    int cnt[8];
    #pragma unroll
    for (int b = 0; b < 8; ++b) cnt[b] = 0;
    for (int rr = rbeg + lane; rr < rend; rr += 64) {
        int bv = bsh[rr];
        #pragma unroll
        for (int b = 0; b < 8; ++b) {
            if (b < N) cnt[b] += __popcll(__ballot(bv == b));
        }
    }
    if (lane == 0) {
        #pragma unroll
        for (int b = 0; b < 8; ++b) wcnt[wave][b] = cnt[b];
    }
    __syncthreads();

    if (tid < 8) {
        int b = tid, acc = 0;
        for (int w = 0; w < 16; ++w) { wbase[w][b] = acc; acc += wcnt[w][b]; }
        baseS[b] = acc;
    }
    __syncthreads();
    if (tid == 0) {
        int acc = 0;
        for (int b = 0; b < N; ++b) { int t = baseS[b]; baseS[b] = acc; acc += t; }
        baseS[N] = acc;
    }
    __syncthreads();

    {
        int off[8];
        #pragma unroll
        for (int b = 0; b < 8; ++b) off[b] = (b < N) ? (baseS[b] + wbase[wave][b]) : 0;
        for (int rr = rbeg + lane; rr < rend; rr += 64) {
            int bv = bsh[rr];
            #pragma unroll
            for (int b = 0; b < 8; ++b) {
                if (b < N) {
                    unsigned long long mask = __ballot(bv == b);
                    if (bv == b) {
                        int pos = off[b] + __popcll(mask & ((1ull << lane) - 1ull));
                        jlist[pos] = rr;
                    }
                    off[b] += __popcll(mask);
                }
            }
        }
    }
    if (tid <= N) base[tid] = baseS[tid];
}

// ---------- plane kernel: TWO planes per block, shared barrier phases -------
__global__ __launch_bounds__(1024, 8) void psroi_plane2_kernel(
    const float* __restrict__ feat, int R, int NPLANES,
    const unsigned short* __restrict__ hshe,
    const unsigned short* __restrict__ wswe,
    const int* __restrict__ jlist, const int* __restrict__ base,
    float* __restrict__ dst)          // ws_T[c][j], j = compacted index
{
    __shared__ float iiA[HH * IW];    // 26.9 KB
    __shared__ float iiB[HH * IW];    // 26.9 KB
    __shared__ float totS[2][NSEG][HH];

    int tid  = threadIdx.x;
    int half = tid >> 9;              // 0: plane A, 1: plane B
    int htid = tid & 511;

    int p = blockIdx.x * 2 + half;
    bool valid = p < NPLANES;
    float* ii = half ? iiB : iiA;

    int b = 0, c = 0, gh = 0, gw = 0;
    if (valid) {
        b = p / CC; c = p % CC;
        int rem = c % (GS * GS);
        gh = rem / GS; gw = rem % GS;
    }

    // ---- stage: each half stages its plane (aligned ds_write_b128) ----
    if (valid) {
        const float4* src4 = (const float4*)(feat + (size_t)p * PLANE);
        for (int i = htid; i < PLANE / 4; i += 512) {
            float4 v = src4[i];
            int h = i / 20;
            int w = (i % 20) * 4;
            *(float4*)(&ii[h * IW + w]) = v;
        }
    }

    // ---- early prefetch of hot-loop gathers (overlap with cumsums) ----
    int j0 = 0, j1 = 0;
    if (valid) { j0 = base[b]; j1 = base[b + 1]; }
    int jA = j0 + htid, jB = jA + 512, jC = jA + 1024, jD = jA + 1536;
    int rA = (valid && jA < j1) ? jlist[jA] : 0;
    int rB = (valid && jB < j1) ? jlist[jB] : 0;
    int rC = (valid && jC < j1) ? jlist[jC] : 0;
    int rD = (valid && jD < j1) ? jlist[jD] : 0;
    unsigned hA = (valid && jA < j1) ? hshe[rA * 7 + gh] : 0;
    unsigned wA = (valid && jA < j1) ? wswe[rA * 7 + gw] : 0;
    unsigned hB = (valid && jB < j1) ? hshe[rB * 7 + gh] : 0;
    unsigned wB = (valid && jB < j1) ? wswe[rB * 7 + gw] : 0;
    unsigned hC = (valid && jC < j1) ? hshe[rC * 7 + gh] : 0;
    unsigned wC = (valid && jC < j1) ? wswe[rC * 7 + gw] : 0;
    unsigned hD = (valid && jD < j1) ? hshe[rD * 7 + gh] : 0;
    unsigned wD = (valid && jD < j1) ? wswe[rD * 7 + gw] : 0;

    __syncthreads();

    bool act = valid && (htid < NSEG * WW);
    int seg = htid / WW;               // 0..4
    int lw  = htid % WW;               // 0..79

    // ---- H cumsum (axis=2 first, as golden): b32, register carry ----
    {
        float v[SEGLEN];
        int col = lw, h0 = seg * SEGLEN;
        if (act) {
            float s = 0.0f;
            #pragma unroll
            for (int k = 0; k < SEGLEN; ++k) { v[k] = ii[(h0 + k) * IW + col]; s += v[k]; }
            totS[half][seg][lw] = s;
        }
        __syncthreads();
        if (act) {
            float off = 0.0f;
            #pragma unroll
            for (int jj = 0; jj < NSEG - 1; ++jj) if (jj < seg) off += totS[half][jj][lw];
            float run = off;
            #pragma unroll
            for (int k = 0; k < SEGLEN; ++k) { run += v[k]; ii[(h0 + k) * IW + col] = run; }
        }
        __syncthreads();
    }
    // ---- W cumsum: b128 float4 segments, register carry ----
    {
        float4 q0, q1, q2, q3;
        int row = lw, w0 = seg * SEGLEN;
        float4* rp = (float4*)&ii[row * IW + w0];
        if (act) {
            q0 = rp[0]; q1 = rp[1]; q2 = rp[2]; q3 = rp[3];
            float s;
            s  = q0.x; s += q0.y; s += q0.z; s += q0.w;
            s += q1.x; s += q1.y; s += q1.z; s += q1.w;
            s += q2.x; s += q2.y; s += q2.z; s += q2.w;
            s += q3.x; s += q3.y; s += q3.z; s += q3.w;
            totS[half][seg][row] = s;
        }
        __syncthreads();
        if (act) {
            float off = 0.0f;
            #pragma unroll
            for (int jj = 0; jj < NSEG - 1; ++jj) if (jj < seg) off += totS[half][jj][row];
            float run = off;
            run += q0.x; q0.x = run; run += q0.y; q0.y = run;
            run += q0.z; q0.z = run; run += q0.w; q0.w = run;
            run += q1.x; q1.x = run; run += q1.y; q1.y = run;
            run += q1.z; q1.z = run; run += q1.w; q1.w = run;
            run += q2.x; q2.x = run; run += q2.y; q2.y = run;
            run += q2.z; q2.z = run; run += q2.w; q2.w = run;
            run += q3.x; q3.x = run; run += q3.y; q3.y = run;
            run += q3.z; q3.z = run; run += q3.w; q3.w = run;
            rp[0] = q0; rp[1] = q1; rp[2] = q2; rp[3] = q3;
        }
        __syncthreads();
    }

    // ---- hot loop: guarded II lookups (II(h,w)=ii[h-1][w-1], 0 if h==0||w==0) ----
    #define IIV(hq, wq) ( ((hq) > 0 && (wq) > 0)                              \
        ? ii[((hq) - 1) * IW + ((wq) - 1)] : 0.0f )
    #define EMIT(jX, hX, wX)                                                  \
    if (valid && jX < j1) {                                                   \
        int hs = hX & 255, he = (int)(hX >> 8);                               \
        int ws = wX & 255, we = (int)(wX >> 8);                               \
        float s = ((IIV(he, we) - IIV(hs, we))                                \
                 -  IIV(he, ws)) + IIV(hs, ws);                               \
        int area = (he - hs) * (we - ws);                                     \
        dst[(size_t)c * R + jX] = (area > 0) ? (s / (float)area) : 0.0f;      \
    }
    EMIT(jA, hA, wA)
    EMIT(jB, hB, wB)
    EMIT(jC, hC, wC)
    EMIT(jD, hD, wD)
    #undef EMIT
    #undef IIV
}

// ---------- transpose: ws_T[1029][R](j-indexed) -> out[R][1029] -------------
__global__ __launch_bounds__(256) void transpose_kernel(
    const float* __restrict__ in, const int* __restrict__ jlist,
    float* __restrict__ out, int R, int C)
{
    __shared__ float t[64][65];
    __shared__ int rows[64];
    int j0 = blockIdx.x * 64;
    int c0 = blockIdx.y * 64;
    int tx = threadIdx.x, ty = threadIdx.y;
    int tid = ty * 64 + tx;

    if (tid < 64 && j0 + tid < R) rows[tid] = jlist[j0 + tid];

    #pragma unroll
    for (int k0 = 0; k0 < 64; k0 += 4) {
        int k = k0 + ty;
        int cc = c0 + k, jj = j0 + tx;
        if (cc < C && jj < R) t[k][tx] = in[(size_t)cc * R + jj];
    }
    __syncthreads();
    #pragma unroll
    for (int k0 = 0; k0 < 64; k0 += 4) {
        int k = k0 + ty;
        int cc = c0 + tx;
        if (j0 + k < R && cc < C) out[(size_t)rows[k] * C + cc] = t[tx][k];
    }
}

// ---------- fallback: correctness-only direct path (ws too small) -----------
__global__ __launch_bounds__(256) void psroi_fallback_kernel(
    const float* __restrict__ feat, const float* __restrict__ rois,
    int R, float* __restrict__ out)
{
    __shared__ float ii[81 * 81];
    int bid = blockIdx.x;
    int b = bid / CC, c = bid % CC;
    int rem = c % 49, gh = rem / 7, gw = rem % 7;

    const float* plane = feat + ((size_t)b * CC + c) * PLANE;
    for (int i = threadIdx.x; i < PLANE; i += 256) {
        int h = i / WW, w = i % WW;
        ii[(h + 1) * 81 + (w + 1)] = plane[i];
    }
    for (int i = threadIdx.x; i < 81; i += 256) { ii[i] = 0.0f; ii[i * 81] = 0.0f; }
    __syncthreads();
    if (threadIdx.x < WW) {
        int w = threadIdx.x + 1; float s = 0.0f;
        for (int h = 1; h <= HH; ++h) { s += ii[h * 81 + w]; ii[h * 81 + w] = s; }
    }
    __syncthreads();
    if (threadIdx.x < HH) {
        int h = threadIdx.x + 1; float* row = &ii[h * 81]; float s = 0.0f;
        for (int w = 1; w <= WW; ++w) { s += row[w]; row[w] = s; }
    }
    __syncthreads();
    for (int r = threadIdx.x; r < R; r += 256) {
        const float* roi = rois + (size_t)r * 5;
        if ((int)roi[0] != b) continue;
        float x1 = rintf(roi[1]) * 0.0625f;
        float y1 = rintf(roi[2]) * 0.0625f;
        float x2 = (rintf(roi[3]) + 1.0f) * 0.0625f;
        float y2 = (rintf(roi[4]) + 1.0f) * 0.0625f;
        float bw = fmaxf(x2 - x1, 0.1f) * recip7();
        float bh = fmaxf(y2 - y1, 0.1f) * recip7();
        asm volatile("" : "+v"(bw), "+v"(bh));
        int hs = (int)fminf(fmaxf(floorf(mul_add_nofma((float)gh,     bh, y1)), 0.0f), 80.0f);
        int he = (int)fminf(fmaxf(ceilf (mul_add_nofma((float)(gh+1), bh, y1)), 0.0f), 80.0f);
        int ws = (int)fminf(fmaxf(floorf(mul_add_nofma((float)gw,     bw, x1)), 0.0f), 80.0f);
        int we = (int)fminf(fmaxf(ceilf (mul_add_nofma((float)(gw+1), bw, x1)), 0.0f), 80.0f);
        float s = ii[he * 81 + we] - ii[hs * 81 + we] - ii[he * 81 + ws] + ii[hs * 81 + ws];
        int area = (he - hs) * (we - ws);
        out[(size_t)r * CC + c] = (area > 0) ? (s / (float)area) : 0.0f;
    }
}

extern "C" void kernel_launch(void* const* d_in, const int* in_sizes, int n_in,
                              void* d_out, int out_size, void* d_ws, size_t ws_size,
                              hipStream_t stream)
{
    const float* feat = (const float*)d_in[0];
    const float* rois = (const float*)d_in[1];
    float* out        = (float*)d_out;

    int R = in_sizes[1] / 5;
    int N = in_sizes[0] / (CC * PLANE);
    int NPLANES = N * CC;

    size_t off_wsT  = 0;
    size_t off_hshe = (off_wsT + (size_t)CC * R * sizeof(float) + 15) & ~(size_t)15;
    size_t off_wswe = off_hshe + (size_t)R * 7 * sizeof(unsigned short);
    size_t off_jl   = (off_wswe + (size_t)R * 7 * sizeof(unsigned short) + 15) & ~(size_t)15;
    size_t off_base = off_jl + (size_t)R * sizeof(int);
    size_t need     = off_base + (size_t)(N + 1) * sizeof(int);

    if (ws_size >= need && N <= 8 && R <= 2048) {
        char* ws = (char*)d_ws;
        float*          ws_T = (float*)(ws + off_wsT);
        unsigned short* hshe = (unsigned short*)(ws + off_hshe);
        unsigned short* wswe = (unsigned short*)(ws + off_wswe);
        int*            jl   = (int*)(ws + off_jl);
        int*            base = (int*)(ws + off_base);

        prep_kernel<<<1, 1024, 0, stream>>>(rois, R, N, hshe, wswe, jl, base);
        psroi_plane2_kernel<<<(NPLANES + 1) / 2, 1024, 0, stream>>>(
            feat, R, NPLANES, hshe, wswe, jl, base, ws_T);
        dim3 blk(64, 4), grd((R + 63) / 64, (CC + 63) / 64);
        transpose_kernel<<<grd, blk, 0, stream>>>(ws_T, jl, out, R, CC);
    } else {
        psroi_fallback_kernel<<<NPLANES, 256, 0, stream>>>(feat, rois, R, out);
    }
}

// Round 18
// 45.562 us; speedup vs baseline: 1.1378x; 1.1378x over previous
//
#include <hip/hip_runtime.h>

#define P   7
#define GS  7
#define D   21
#define HH  80
#define WW  80
#define CC  (D * GS * GS)        // 1029
#define PLANE (HH * WW)          // 6400 floats
#define IW  84                   // row stride: 16B-aligned rows, bank-stride 20 mod 32
#define NSEG 5
#define SEGLEN 16

// fl32(1/7) = 0x3E124925 — the golden divides via reciprocal multiply.
__device__ __forceinline__ float recip7() {
    union { unsigned u; float f; } c; c.u = 0x3E124925u; return c.f;
}

// a*b + c with a HARD barrier between mul and add: no fma contraction ever.
__device__ __forceinline__ float mul_add_nofma(float a, float b, float c) {
    float t = a * b;
    asm volatile("" : "+v"(t));
    return t + c;
}

// ---------- prep: edges + parallel 2-level ballot compaction, one block -----
__global__ __launch_bounds__(1024) void prep_kernel(
    const float* __restrict__ rois, int R, int N,
    unsigned short* __restrict__ hshe,
    unsigned short* __restrict__ wswe,
    int* __restrict__ jlist, int* __restrict__ base)
{
    __shared__ unsigned char bsh[2048];
    __shared__ int wcnt[16][8];
    __shared__ int wbase[16][8];
    __shared__ int baseS[9];
    int tid = threadIdx.x, wave = tid >> 6, lane = tid & 63;

    for (int r = tid; r < R; r += 1024) {
        const float* roi = rois + (size_t)r * 5;
        bsh[r] = (unsigned char)(int)roi[0];

        float x1 = rintf(roi[1]) * 0.0625f;
        float y1 = rintf(roi[2]) * 0.0625f;
        float x2 = (rintf(roi[3]) + 1.0f) * 0.0625f;
        float y2 = (rintf(roi[4]) + 1.0f) * 0.0625f;
        float bin_w = fmaxf(x2 - x1, 0.1f) * recip7();
        float bin_h = fmaxf(y2 - y1, 0.1f) * recip7();
        asm volatile("" : "+v"(bin_w), "+v"(bin_h));

        #pragma unroll
        for (int g = 0; g < 7; ++g) {
            float hs_f = floorf(mul_add_nofma((float)g,       bin_h, y1));
            float he_f = ceilf (mul_add_nofma((float)(g + 1), bin_h, y1));
            float ws_f = floorf(mul_add_nofma((float)g,       bin_w, x1));
            float we_f = ceilf (mul_add_nofma((float)(g + 1), bin_w, x1));
            int hs = (int)fminf(fmaxf(hs_f, 0.0f), 80.0f);
            int he = (int)fminf(fmaxf(he_f, 0.0f), 80.0f);
            int ws = (int)fminf(fmaxf(ws_f, 0.0f), 80.0f);
            int we = (int)fminf(fmaxf(we_f, 0.0f), 80.0f);
            hshe[r * 7 + g] = (unsigned short)(hs | (he << 8));
            wswe[r * 7 + g] = (unsigned short)(ws | (we << 8));
        }
    }
    __syncthreads();

    int chunk = (R + 15) / 16;
    int rbeg = wave * chunk;
    int rend = min(rbeg + chunk, R);
    int cnt[8];
    #pragma unroll
    for (int b = 0; b < 8; ++b) cnt[b] = 0;
    for (int rr = rbeg + lane; rr < rend; rr += 64) {
        int bv = bsh[rr];
        #pragma unroll
        for (int b = 0; b < 8; ++b) {
            if (b < N) cnt[b] += __popcll(__ballot(bv == b));
        }
    }
    if (lane == 0) {
        #pragma unroll
        for (int b = 0; b < 8; ++b) wcnt[wave][b] = cnt[b];
    }
    __syncthreads();

    if (tid < 8) {
        int b = tid, acc = 0;
        for (int w = 0; w < 16; ++w) { wbase[w][b] = acc; acc += wcnt[w][b]; }
        baseS[b] = acc;
    }
    __syncthreads();
    if (tid == 0) {
        int acc = 0;
        for (int b = 0; b < N; ++b) { int t = baseS[b]; baseS[b] = acc; acc += t; }
        baseS[N] = acc;
    }
    __syncthreads();

    {
        int off[8];
        #pragma unroll
        for (int b = 0; b < 8; ++b) off[b] = (b < N) ? (baseS[b] + wbase[wave][b]) : 0;
        for (int rr = rbeg + lane; rr < rend; rr += 64) {
            int bv = bsh[rr];
            #pragma unroll
            for (int b = 0; b < 8; ++b) {
                if (b < N) {
                    unsigned long long mask = __ballot(bv == b);
                    if (bv == b) {
                        int pos = off[b] + __popcll(mask & ((1ull << lane) - 1ull));
                        jlist[pos] = rr;
                    }
                    off[b] += __popcll(mask);
                }
            }
        }
    }
    if (tid <= N) base[tid] = baseS[tid];
}

// ---------- plane kernel: b128 LDS integral image + guarded O(1) hot loop ---
__global__ __launch_bounds__(512) void psroi_plane_kernel(
    const float* __restrict__ feat, int R,
    const unsigned short* __restrict__ hshe,
    const unsigned short* __restrict__ wswe,
    const int* __restrict__ jlist, const int* __restrict__ base,
    float* __restrict__ dst)          // ws_T[c][j], j = compacted index
{
    __shared__ float ii[HH * IW];     // [80][84], no border; cols 80..83 junk
    __shared__ float tot[NSEG][HH];   // 1.6 KB

    int tid = threadIdx.x;
    int bid = blockIdx.x;
    int b   = bid / CC;
    int c   = bid % CC;
    int rem = c % (GS * GS);
    int gh  = rem / GS;
    int gw  = rem % GS;

    // ---- stage plane: aligned ds_write_b128 (row*84 + 4k is 16B-aligned) ----
    const float4* src4 = (const float4*)(feat + ((size_t)b * CC + c) * PLANE);
    for (int i = tid; i < PLANE / 4; i += 512) {
        float4 v = src4[i];
        int h = i / 20;
        int w = (i % 20) * 4;
        *(float4*)(&ii[h * IW + w]) = v;
    }

    // ---- early prefetch of hot-loop gathers (overlap with cumsums) ----
    int j0 = base[b], j1 = base[b + 1];
    int jA = j0 + tid, jB = jA + 512, jC = jA + 1024, jD = jA + 1536;
    int rA = (jA < j1) ? jlist[jA] : 0;
    int rB = (jB < j1) ? jlist[jB] : 0;
    int rC = (jC < j1) ? jlist[jC] : 0;
    int rD = (jD < j1) ? jlist[jD] : 0;
    unsigned hA = (jA < j1) ? hshe[rA * 7 + gh] : 0;
    unsigned wA = (jA < j1) ? wswe[rA * 7 + gw] : 0;
    unsigned hB = (jB < j1) ? hshe[rB * 7 + gh] : 0;
    unsigned wB = (jB < j1) ? wswe[rB * 7 + gw] : 0;
    unsigned hC = (jC < j1) ? hshe[rC * 7 + gh] : 0;
    unsigned wC = (jC < j1) ? wswe[rC * 7 + gw] : 0;
    unsigned hD = (jD < j1) ? hshe[rD * 7 + gh] : 0;
    unsigned wD = (jD < j1) ? wswe[rD * 7 + gw] : 0;

    __syncthreads();

    bool act = tid < NSEG * WW;
    int seg = tid / WW;                // 0..4
    int lw  = tid % WW;                // 0..79

    // ---- H cumsum (axis=2 first, as golden): b32, register carry ----
    {
        float v[SEGLEN];
        int col = lw, h0 = seg * SEGLEN;
        if (act) {
            float s = 0.0f;
            #pragma unroll
            for (int k = 0; k < SEGLEN; ++k) { v[k] = ii[(h0 + k) * IW + col]; s += v[k]; }
            tot[seg][lw] = s;
        }
        __syncthreads();
        if (act) {
            float off = 0.0f;
            #pragma unroll
            for (int jj = 0; jj < NSEG - 1; ++jj) if (jj < seg) off += tot[jj][lw];
            float run = off;
            #pragma unroll
            for (int k = 0; k < SEGLEN; ++k) { run += v[k]; ii[(h0 + k) * IW + col] = run; }
        }
        __syncthreads();
    }
    // ---- W cumsum: b128 float4 segments, register carry ----
    {
        float4 q0, q1, q2, q3;
        int row = lw, w0 = seg * SEGLEN;
        float4* rp = (float4*)&ii[row * IW + w0];
        if (act) {
            q0 = rp[0]; q1 = rp[1]; q2 = rp[2]; q3 = rp[3];
            float s;
            s  = q0.x; s += q0.y; s += q0.z; s += q0.w;
            s += q1.x; s += q1.y; s += q1.z; s += q1.w;
            s += q2.x; s += q2.y; s += q2.z; s += q2.w;
            s += q3.x; s += q3.y; s += q3.z; s += q3.w;
            tot[seg][row] = s;
        }
        __syncthreads();
        if (act) {
            float off = 0.0f;
            #pragma unroll
            for (int jj = 0; jj < NSEG - 1; ++jj) if (jj < seg) off += tot[jj][row];
            float run = off;
            run += q0.x; q0.x = run; run += q0.y; q0.y = run;
            run += q0.z; q0.z = run; run += q0.w; q0.w = run;
            run += q1.x; q1.x = run; run += q1.y; q1.y = run;
            run += q1.z; q1.z = run; run += q1.w; q1.w = run;
            run += q2.x; q2.x = run; run += q2.y; q2.y = run;
            run += q2.z; q2.z = run; run += q2.w; q2.w = run;
            run += q3.x; q3.x = run; run += q3.y; q3.y = run;
            run += q3.z; q3.z = run; run += q3.w; q3.w = run;
            rp[0] = q0; rp[1] = q1; rp[2] = q2; rp[3] = q3;
        }
        __syncthreads();
    }

    // ---- hot loop: guarded II lookups (II(h,w)=ii[h-1][w-1], 0 if h==0||w==0) ----
    #define IIV(hq, wq) ( ((hq) > 0 && (wq) > 0)                              \
        ? ii[((hq) - 1) * IW + ((wq) - 1)] : 0.0f )
    #define EMIT(jX, hX, wX)                                                  \
    if (jX < j1) {                                                            \
        int hs = hX & 255, he = (int)(hX >> 8);                               \
        int ws = wX & 255, we = (int)(wX >> 8);                               \
        float s = ((IIV(he, we) - IIV(hs, we))                                \
                 -  IIV(he, ws)) + IIV(hs, ws);                               \
        int area = (he - hs) * (we - ws);                                     \
        dst[(size_t)c * R + jX] = (area > 0) ? (s / (float)area) : 0.0f;      \
    }
    EMIT(jA, hA, wA)
    EMIT(jB, hB, wB)
    EMIT(jC, hC, wC)
    EMIT(jD, hD, wD)
    #undef EMIT
    #undef IIV
}

// ---------- transpose: ws_T[1029][R](j-indexed) -> out[R][1029] -------------
__global__ __launch_bounds__(256) void transpose_kernel(
    const float* __restrict__ in, const int* __restrict__ jlist,
    float* __restrict__ out, int R, int C)
{
    __shared__ float t[64][65];
    __shared__ int rows[64];
    int j0 = blockIdx.x * 64;
    int c0 = blockIdx.y * 64;
    int tx = threadIdx.x, ty = threadIdx.y;
    int tid = ty * 64 + tx;

    if (tid < 64 && j0 + tid < R) rows[tid] = jlist[j0 + tid];

    #pragma unroll
    for (int k0 = 0; k0 < 64; k0 += 4) {
        int k = k0 + ty;
        int cc = c0 + k, jj = j0 + tx;
        if (cc < C && jj < R) t[k][tx] = in[(size_t)cc * R + jj];
    }
    __syncthreads();
    #pragma unroll
    for (int k0 = 0; k0 < 64; k0 += 4) {
        int k = k0 + ty;
        int cc = c0 + tx;
        if (j0 + k < R && cc < C) out[(size_t)rows[k] * C + cc] = t[tx][k];
    }
}

// ---------- fallback: correctness-only direct path (ws too small) -----------
__global__ __launch_bounds__(256) void psroi_fallback_kernel(
    const float* __restrict__ feat, const float* __restrict__ rois,
    int R, float* __restrict__ out)
{
    __shared__ float ii[81 * 81];
    int bid = blockIdx.x;
    int b = bid / CC, c = bid % CC;
    int rem = c % 49, gh = rem / 7, gw = rem % 7;

    const float* plane = feat + ((size_t)b * CC + c) * PLANE;
    for (int i = threadIdx.x; i < PLANE; i += 256) {
        int h = i / WW, w = i % WW;
        ii[(h + 1) * 81 + (w + 1)] = plane[i];
    }
    for (int i = threadIdx.x; i < 81; i += 256) { ii[i] = 0.0f; ii[i * 81] = 0.0f; }
    __syncthreads();
    if (threadIdx.x < WW) {
        int w = threadIdx.x + 1; float s = 0.0f;
        for (int h = 1; h <= HH; ++h) { s += ii[h * 81 + w]; ii[h * 81 + w] = s; }
    }
    __syncthreads();
    if (threadIdx.x < HH) {
        int h = threadIdx.x + 1; float* row = &ii[h * 81]; float s = 0.0f;
        for (int w = 1; w <= WW; ++w) { s += row[w]; row[w] = s; }
    }
    __syncthreads();
    for (int r = threadIdx.x; r < R; r += 256) {
        const float* roi = rois + (size_t)r * 5;
        if ((int)roi[0] != b) continue;
        float x1 = rintf(roi[1]) * 0.0625f;
        float y1 = rintf(roi[2]) * 0.0625f;
        float x2 = (rintf(roi[3]) + 1.0f) * 0.0625f;
        float y2 = (rintf(roi[4]) + 1.0f) * 0.0625f;
        float bw = fmaxf(x2 - x1, 0.1f) * recip7();
        float bh = fmaxf(y2 - y1, 0.1f) * recip7();
        asm volatile("" : "+v"(bw), "+v"(bh));
        int hs = (int)fminf(fmaxf(floorf(mul_add_nofma((float)gh,     bh, y1)), 0.0f), 80.0f);
        int he = (int)fminf(fmaxf(ceilf (mul_add_nofma((float)(gh+1), bh, y1)), 0.0f), 80.0f);
        int ws = (int)fminf(fmaxf(floorf(mul_add_nofma((float)gw,     bw, x1)), 0.0f), 80.0f);
        int we = (int)fminf(fmaxf(ceilf (mul_add_nofma((float)(gw+1), bw, x1)), 0.0f), 80.0f);
        float s = ii[he * 81 + we] - ii[hs * 81 + we] - ii[he * 81 + ws] + ii[hs * 81 + ws];
        int area = (he - hs) * (we - ws);
        out[(size_t)r * CC + c] = (area > 0) ? (s / (float)area) : 0.0f;
    }
}

extern "C" void kernel_launch(void* const* d_in, const int* in_sizes, int n_in,
                              void* d_out, int out_size, void* d_ws, size_t ws_size,
                              hipStream_t stream)
{
    const float* feat = (const float*)d_in[0];
    const float* rois = (const float*)d_in[1];
    float* out        = (float*)d_out;

    int R = in_sizes[1] / 5;
    int N = in_sizes[0] / (CC * PLANE);

    size_t off_wsT  = 0;
    size_t off_hshe = (off_wsT + (size_t)CC * R * sizeof(float) + 15) & ~(size_t)15;
    size_t off_wswe = off_hshe + (size_t)R * 7 * sizeof(unsigned short);
    size_t off_jl   = (off_wswe + (size_t)R * 7 * sizeof(unsigned short) + 15) & ~(size_t)15;
    size_t off_base = off_jl + (size_t)R * sizeof(int);
    size_t need     = off_base + (size_t)(N + 1) * sizeof(int);

    bool chunk_ok = (((R + 15) / 16) % 64) == 0;

    if (ws_size >= need && N <= 8 && R <= 2048 && chunk_ok) {
        char* ws = (char*)d_ws;
        float*          ws_T = (float*)(ws + off_wsT);
        unsigned short* hshe = (unsigned short*)(ws + off_hshe);
        unsigned short* wswe = (unsigned short*)(ws + off_wswe);
        int*            jl   = (int*)(ws + off_jl);
        int*            base = (int*)(ws + off_base);

        prep_kernel<<<1, 1024, 0, stream>>>(rois, R, N, hshe, wswe, jl, base);
        psroi_plane_kernel<<<N * CC, 512, 0, stream>>>(feat, R, hshe, wswe, jl, base, ws_T);
        dim3 blk(64, 4), grd((R + 63) / 64, (CC + 63) / 64);
        transpose_kernel<<<grd, blk, 0, stream>>>(ws_T, jl, out, R, CC);
    } else {
        psroi_fallback_kernel<<<N * CC, 256, 0, stream>>>(feat, rois, R, out);
    }
}

// Round 19
// 43.538 us; speedup vs baseline: 1.1907x; 1.0465x over previous
//
#include <hip/hip_runtime.h>

#define P   7
#define GS  7
#define D   21
#define HH  80
#define WW  80
#define CC  (D * GS * GS)        // 1029
#define PLANE (HH * WW)          // 6400 floats
#define IW  84                   // row stride: 16B-aligned rows
#define NSEG 5
#define SEGLEN 16

// fl32(1/7) = 0x3E124925 — the golden divides via reciprocal multiply.
__device__ __forceinline__ float recip7() {
    union { unsigned u; float f; } c; c.u = 0x3E124925u; return c.f;
}

// a*b + c with a HARD barrier between mul and add: no fma contraction ever.
__device__ __forceinline__ float mul_add_nofma(float a, float b, float c) {
    float t = a * b;
    asm volatile("" : "+v"(t));
    return t + c;
}

// Packed edges for one ROI at this block's (gh, gw): hs|he<<8, ws|we<<8.
// Arithmetic byte-identical to the previously passing table version.
__device__ __forceinline__ void edges_for(const float* __restrict__ roi,
                                          int gh, int gw,
                                          unsigned& hp, unsigned& wp)
{
    float x1 = rintf(roi[1]) * 0.0625f;
    float y1 = rintf(roi[2]) * 0.0625f;
    float x2 = (rintf(roi[3]) + 1.0f) * 0.0625f;
    float y2 = (rintf(roi[4]) + 1.0f) * 0.0625f;
    float bin_w = fmaxf(x2 - x1, 0.1f) * recip7();
    float bin_h = fmaxf(y2 - y1, 0.1f) * recip7();
    asm volatile("" : "+v"(bin_w), "+v"(bin_h));
    int hs = (int)fminf(fmaxf(floorf(mul_add_nofma((float)gh,       bin_h, y1)), 0.0f), 80.0f);
    int he = (int)fminf(fmaxf(ceilf (mul_add_nofma((float)(gh + 1), bin_h, y1)), 0.0f), 80.0f);
    int ws = (int)fminf(fmaxf(floorf(mul_add_nofma((float)gw,       bin_w, x1)), 0.0f), 80.0f);
    int we = (int)fminf(fmaxf(ceilf (mul_add_nofma((float)(gw + 1), bin_w, x1)), 0.0f), 80.0f);
    hp = (unsigned)(hs | (he << 8));
    wp = (unsigned)(ws | (we << 8));
}

// ---------- prep: compaction ONLY (2-level ballot), one block ---------------
__global__ __launch_bounds__(1024) void prep_kernel(
    const float* __restrict__ rois, int R, int N,
    int* __restrict__ jlist, int* __restrict__ base)
{
    __shared__ unsigned char bsh[2048];
    __shared__ int wcnt[16][8];
    __shared__ int wbase[16][8];
    __shared__ int baseS[9];
    int tid = threadIdx.x, wave = tid >> 6, lane = tid & 63;

    for (int r = tid; r < R; r += 1024)
        bsh[r] = (unsigned char)(int)rois[(size_t)r * 5];
    __syncthreads();

    int chunk = (R + 15) / 16;
    int rbeg = wave * chunk;
    int rend = min(rbeg + chunk, R);
    int cnt[8];
    #pragma unroll
    for (int b = 0; b < 8; ++b) cnt[b] = 0;
    for (int rr = rbeg + lane; rr < rend; rr += 64) {
        int bv = bsh[rr];
        #pragma unroll
        for (int b = 0; b < 8; ++b) {
            if (b < N) cnt[b] += __popcll(__ballot(bv == b));
        }
    }
    if (lane == 0) {
        #pragma unroll
        for (int b = 0; b < 8; ++b) wcnt[wave][b] = cnt[b];
    }
    __syncthreads();

    if (tid < 8) {
        int b = tid, acc = 0;
        for (int w = 0; w < 16; ++w) { wbase[w][b] = acc; acc += wcnt[w][b]; }
        baseS[b] = acc;
    }
    __syncthreads();
    if (tid == 0) {
        int acc = 0;
        for (int b = 0; b < N; ++b) { int t = baseS[b]; baseS[b] = acc; acc += t; }
        baseS[N] = acc;
    }
    __syncthreads();

    {
        int off[8];
        #pragma unroll
        for (int b = 0; b < 8; ++b) off[b] = (b < N) ? (baseS[b] + wbase[wave][b]) : 0;
        for (int rr = rbeg + lane; rr < rend; rr += 64) {
            int bv = bsh[rr];
            #pragma unroll
            for (int b = 0; b < 8; ++b) {
                if (b < N) {
                    unsigned long long mask = __ballot(bv == b);
                    if (bv == b) {
                        int pos = off[b] + __popcll(mask & ((1ull << lane) - 1ull));
                        jlist[pos] = rr;
                    }
                    off[b] += __popcll(mask);
                }
            }
        }
    }
    if (tid <= N) base[tid] = baseS[tid];
}

// ---------- plane kernel: inline edges + b128 II + guarded O(1) hot loop ----
__global__ __launch_bounds__(512) void psroi_plane_kernel(
    const float* __restrict__ feat, const float* __restrict__ rois, int R,
    const int* __restrict__ jlist, const int* __restrict__ base,
    float* __restrict__ dst)          // ws_T[c][j], j = compacted index
{
    __shared__ float ii[HH * IW];     // [80][84], no border; cols 80..83 junk
    __shared__ float tot[NSEG][HH];   // 1.6 KB

    int tid = threadIdx.x;
    int bid = blockIdx.x;
    int b   = bid / CC;
    int c   = bid % CC;
    int rem = c % (GS * GS);
    int gh  = rem / GS;
    int gw  = rem % GS;

    // ---- stage plane: aligned ds_write_b128 ----
    const float4* src4 = (const float4*)(feat + ((size_t)b * CC + c) * PLANE);
    for (int i = tid; i < PLANE / 4; i += 512) {
        float4 v = src4[i];
        int h = i / 20;
        int w = (i % 20) * 4;
        *(float4*)(&ii[h * IW + w]) = v;
    }

    // ---- prefetch + INLINE edge math (overlaps stage + cumsums) ----
    int j0 = base[b], j1 = base[b + 1];
    int jA = j0 + tid, jB = jA + 512, jC = jA + 1024, jD = jA + 1536;
    unsigned hA = 0, wA = 0, hB = 0, wB = 0, hC = 0, wC = 0, hD = 0, wD = 0;
    if (jA < j1) edges_for(rois + (size_t)jlist[jA] * 5, gh, gw, hA, wA);
    if (jB < j1) edges_for(rois + (size_t)jlist[jB] * 5, gh, gw, hB, wB);
    if (jC < j1) edges_for(rois + (size_t)jlist[jC] * 5, gh, gw, hC, wC);
    if (jD < j1) edges_for(rois + (size_t)jlist[jD] * 5, gh, gw, hD, wD);

    __syncthreads();

    bool act = tid < NSEG * WW;
    int seg = tid / WW;                // 0..4
    int lw  = tid % WW;                // 0..79

    // ---- H cumsum (axis=2 first, as golden): b32, register carry ----
    {
        float v[SEGLEN];
        int col = lw, h0 = seg * SEGLEN;
        if (act) {
            float s = 0.0f;
            #pragma unroll
            for (int k = 0; k < SEGLEN; ++k) { v[k] = ii[(h0 + k) * IW + col]; s += v[k]; }
            tot[seg][lw] = s;
        }
        __syncthreads();
        if (act) {
            float off = 0.0f;
            #pragma unroll
            for (int jj = 0; jj < NSEG - 1; ++jj) if (jj < seg) off += tot[jj][lw];
            float run = off;
            #pragma unroll
            for (int k = 0; k < SEGLEN; ++k) { run += v[k]; ii[(h0 + k) * IW + col] = run; }
        }
        __syncthreads();
    }
    // ---- W cumsum: b128 float4 segments, register carry ----
    {
        float4 q0, q1, q2, q3;
        int row = lw, w0 = seg * SEGLEN;
        float4* rp = (float4*)&ii[row * IW + w0];
        if (act) {
            q0 = rp[0]; q1 = rp[1]; q2 = rp[2]; q3 = rp[3];
            float s;
            s  = q0.x; s += q0.y; s += q0.z; s += q0.w;
            s += q1.x; s += q1.y; s += q1.z; s += q1.w;
            s += q2.x; s += q2.y; s += q2.z; s += q2.w;
            s += q3.x; s += q3.y; s += q3.z; s += q3.w;
            tot[seg][row] = s;
        }
        __syncthreads();
        if (act) {
            float off = 0.0f;
            #pragma unroll
            for (int jj = 0; jj < NSEG - 1; ++jj) if (jj < seg) off += tot[jj][row];
            float run = off;
            run += q0.x; q0.x = run; run += q0.y; q0.y = run;
            run += q0.z; q0.z = run; run += q0.w; q0.w = run;
            run += q1.x; q1.x = run; run += q1.y; q1.y = run;
            run += q1.z; q1.z = run; run += q1.w; q1.w = run;
            run += q2.x; q2.x = run; run += q2.y; q2.y = run;
            run += q2.z; q2.z = run; run += q2.w; q2.w = run;
            run += q3.x; q3.x = run; run += q3.y; q3.y = run;
            run += q3.z; q3.z = run; run += q3.w; q3.w = run;
            rp[0] = q0; rp[1] = q1; rp[2] = q2; rp[3] = q3;
        }
        __syncthreads();
    }

    // ---- hot loop: guarded II lookups (II(h,w)=ii[h-1][w-1], 0 if h==0||w==0) ----
    #define IIV(hq, wq) ( ((hq) > 0 && (wq) > 0)                              \
        ? ii[((hq) - 1) * IW + ((wq) - 1)] : 0.0f )
    #define EMIT(jX, hX, wX)                                                  \
    if (jX < j1) {                                                            \
        int hs = hX & 255, he = (int)(hX >> 8);                               \
        int ws = wX & 255, we = (int)(wX >> 8);                               \
        float s = ((IIV(he, we) - IIV(hs, we))                                \
                 -  IIV(he, ws)) + IIV(hs, ws);                               \
        int area = (he - hs) * (we - ws);                                     \
        dst[(size_t)c * R + jX] = (area > 0) ? (s / (float)area) : 0.0f;      \
    }
    EMIT(jA, hA, wA)
    EMIT(jB, hB, wB)
    EMIT(jC, hC, wC)
    EMIT(jD, hD, wD)
    #undef EMIT
    #undef IIV
}

// ---------- transpose: ws_T[1029][R](j-indexed) -> out[R][1029] -------------
__global__ __launch_bounds__(256) void transpose_kernel(
    const float* __restrict__ in, const int* __restrict__ jlist,
    float* __restrict__ out, int R, int C)
{
    __shared__ float t[64][65];
    __shared__ int rows[64];
    int j0 = blockIdx.x * 64;
    int c0 = blockIdx.y * 64;
    int tx = threadIdx.x, ty = threadIdx.y;
    int tid = ty * 64 + tx;

    if (tid < 64 && j0 + tid < R) rows[tid] = jlist[j0 + tid];

    #pragma unroll
    for (int k0 = 0; k0 < 64; k0 += 4) {
        int k = k0 + ty;
        int cc = c0 + k, jj = j0 + tx;
        if (cc < C && jj < R) t[k][tx] = in[(size_t)cc * R + jj];
    }
    __syncthreads();
    #pragma unroll
    for (int k0 = 0; k0 < 64; k0 += 4) {
        int k = k0 + ty;
        int cc = c0 + tx;
        if (j0 + k < R && cc < C) out[(size_t)rows[k] * C + cc] = t[tx][k];
    }
}

// ---------- fallback: correctness-only direct path (ws too small) -----------
__global__ __launch_bounds__(256) void psroi_fallback_kernel(
    const float* __restrict__ feat, const float* __restrict__ rois,
    int R, float* __restrict__ out)
{
    __shared__ float ii[81 * 81];
    int bid = blockIdx.x;
    int b = bid / CC, c = bid % CC;
    int rem = c % 49, gh = rem / 7, gw = rem % 7;

    const float* plane = feat + ((size_t)b * CC + c) * PLANE;
    for (int i = threadIdx.x; i < PLANE; i += 256) {
        int h = i / WW, w = i % WW;
        ii[(h + 1) * 81 + (w + 1)] = plane[i];
    }
    for (int i = threadIdx.x; i < 81; i += 256) { ii[i] = 0.0f; ii[i * 81] = 0.0f; }
    __syncthreads();
    if (threadIdx.x < WW) {
        int w = threadIdx.x + 1; float s = 0.0f;
        for (int h = 1; h <= HH; ++h) { s += ii[h * 81 + w]; ii[h * 81 + w] = s; }
    }
    __syncthreads();
    if (threadIdx.x < HH) {
        int h = threadIdx.x + 1; float* row = &ii[h * 81]; float s = 0.0f;
        for (int w = 1; w <= WW; ++w) { s += row[w]; row[w] = s; }
    }
    __syncthreads();
    for (int r = threadIdx.x; r < R; r += 256) {
        const float* roi = rois + (size_t)r * 5;
        if ((int)roi[0] != b) continue;
        unsigned hp, wp;
        edges_for(roi, gh, gw, hp, wp);
        int hs = hp & 255, he = (int)(hp >> 8);
        int ws = wp & 255, we = (int)(wp >> 8);
        float s = ii[he * 81 + we] - ii[hs * 81 + we] - ii[he * 81 + ws] + ii[hs * 81 + ws];
        int area = (he - hs) * (we - ws);
        out[(size_t)r * CC + c] = (area > 0) ? (s / (float)area) : 0.0f;
    }
}

extern "C" void kernel_launch(void* const* d_in, const int* in_sizes, int n_in,
                              void* d_out, int out_size, void* d_ws, size_t ws_size,
                              hipStream_t stream)
{
    const float* feat = (const float*)d_in[0];
    const float* rois = (const float*)d_in[1];
    float* out        = (float*)d_out;

    int R = in_sizes[1] / 5;
    int N = in_sizes[0] / (CC * PLANE);

    size_t off_wsT  = 0;
    size_t off_jl   = (off_wsT + (size_t)CC * R * sizeof(float) + 15) & ~(size_t)15;
    size_t off_base = off_jl + (size_t)R * sizeof(int);
    size_t need     = off_base + (size_t)(N + 1) * sizeof(int);

    bool chunk_ok = (((R + 15) / 16) % 64) == 0;

    if (ws_size >= need && N <= 8 && R <= 2048 && chunk_ok) {
        char* ws = (char*)d_ws;
        float* ws_T = (float*)(ws + off_wsT);
        int*   jl   = (int*)(ws + off_jl);
        int*   base = (int*)(ws + off_base);

        prep_kernel<<<1, 1024, 0, stream>>>(rois, R, N, jl, base);
        psroi_plane_kernel<<<N * CC, 512, 0, stream>>>(feat, rois, R, jl, base, ws_T);
        dim3 blk(64, 4), grd((R + 63) / 64, (CC + 63) / 64);
        transpose_kernel<<<grd, blk, 0, stream>>>(ws_T, jl, out, R, CC);
    } else {
        psroi_fallback_kernel<<<N * CC, 256, 0, stream>>>(feat, rois, R, out);
    }
}